// Round 11
// baseline (68.811 us; speedup 1.0000x reference)
//
#include <hip/hip_runtime.h>

#define TT 20
#define NSTK 1000
#define THREADS 256
#define XP 72               // padded f16 row stride: 144 B -> exactly-4 addrs/bank-window (optimal)

#define SC_SIG  1.44269504089f      // log2(e)
#define SC_TANH 2.88539008178f      // 2*log2(e)

typedef float f32x4 __attribute__((ext_vector_type(4)));
typedef _Float16 f16x8 __attribute__((ext_vector_type(8)));
typedef _Float16 f16x2 __attribute__((ext_vector_type(2)));

__device__ __forceinline__ float rcp_f(float x) { return __builtin_amdgcn_rcpf(x); }
__device__ __forceinline__ float exp2_f(float x) { return __builtin_amdgcn_exp2f(x); }

// A/B fragment k-convention: k = kf*32 + q*8 + j  (q = lane>>4, j = elem).
// Same bijection for A and B, so the true HW k-permutation cancels.
// A-operands are read straight from row-major padded LDS rows:
//   af[kf] for lane (q, r16): 16 B at [row = r16&7][(kf&1)*32 + q*8]  (x: kf 0,1; h: kf 2,3)
// Rows r16>=8 duplicate r16-8 (same LDS addr -> broadcast, free); their C rows are discarded.

extern "C" __global__ void __launch_bounds__(THREADS, 3)
lstm_att_lean(const float* __restrict__ x,
              const float* __restrict__ Wi, const float* __restrict__ bi,
              const float* __restrict__ Wo, const float* __restrict__ bo,
              const float* __restrict__ Wf, const float* __restrict__ bf_,
              const float* __restrict__ Wc, const float* __restrict__ bc,
              const float* __restrict__ Wt,
              float* __restrict__ out)
{
    __shared__ __align__(16) _Float16 xs[TT][8][XP];      // 22.5 KB  all-t x, f16
    __shared__ __align__(16) _Float16 hh[TT + 1][8][XP];  // 23.6 KB  h history (hh[0]=0)

    const int n    = blockIdx.x;
    const int tid  = threadIdx.x;
    const int lane = tid & 63;
    const int w    = tid >> 6;            // wave 0..3
    const int q    = lane >> 4;           // k-subgroup
    const int r16  = lane & 15;           // A row / B col within frag
    const int brow = r16 & 7;             // batch row this lane reads (8-15 dup -> broadcast)
    const int dcol = w * 16 + r16;        // this lane's d column (0..63)
    const bool hi  = lane >= 32;
    const int rowbase = ((lane & 31) >> 4) * 4 + (hi ? 2 : 0);  // this lane's 2 batch rows

    // ---- issue x loads first (oldest in vmcnt FIFO; small, coalesced) ----
    const int xrow = tid >> 5;            // row offset within a sweep
    const int xd   = (tid & 31) * 2;
    float2 xr[TT];
    #pragma unroll
    for (int u = 0; u < TT; ++u) {
        const int r = u * 8 + xrow;       // flat (b*20+t) row, 0..159
        xr[u] = *(const float2*)(x + ((size_t)r * NSTK + n) * 64 + xd);
    }

    // ---- weight B-frags, strided scalar loads (R4 pattern), log2e-prescaled ----
    f16x8 bw[4][4];
    float biasv[4];
    {
        const float* Wg[4] = {Wi, Wo, Wf, Wc};
        const float* Bg[4] = {bi, bo, bf_, bc};
        #pragma unroll
        for (int g = 0; g < 4; ++g) {
            const float sc = (g == 3) ? SC_TANH : SC_SIG;
            const float* base = Wg[g] + (size_t)n * 8192 + dcol;
            #pragma unroll
            for (int kf = 0; kf < 4; ++kf)
                #pragma unroll
                for (int j = 0; j < 8; ++j)
                    bw[g][kf][j] = (_Float16)(base[(kf * 32 + q * 8 + j) * 64] * sc);
            biasv[g] = Bg[g][n * 64 + dcol] * sc;
        }
    }

    // ---- store x into LDS (f16), zero hh[0] ----
    #pragma unroll
    for (int u = 0; u < TT; ++u) {
        const int r = u * 8 + xrow;
        const int b = r / TT, t = r % TT;
        *(f16x2*)(&xs[t][b][xd]) = (f16x2){(_Float16)xr[u].x, (_Float16)xr[u].y};
    }
    for (int i = tid; i < 8 * XP / 2; i += THREADS) ((unsigned*)hh)[i] = 0u;

    float cst0 = 0.f, cst1 = 0.f;         // cell state for rows rowbase, rowbase+1 at dcol
    __syncthreads();

    for (int t = 0; t < TT; ++t) {
        // A-operands: 4 x ds_read_b128, conflict-optimal, zero VMEM in the whole phase
        f16x8 af[4];
        af[0] = *(const f16x8*)(&xs[t][brow][q * 8]);
        af[1] = *(const f16x8*)(&xs[t][brow][32 + q * 8]);
        af[2] = *(const f16x8*)(&hh[t][brow][q * 8]);
        af[3] = *(const f16x8*)(&hh[t][brow][32 + q * 8]);

        f32x4 acc[4];
        #pragma unroll
        for (int g = 0; g < 4; ++g)
            acc[g] = (f32x4){biasv[g], biasv[g], biasv[g], biasv[g]};
        #pragma unroll
        for (int kf = 0; kf < 4; ++kf) {
            #pragma unroll
            for (int g = 0; g < 4; ++g)
                acc[g] = __builtin_amdgcn_mfma_f32_16x16x32_f16(af[kf], bw[g][kf], acc[g], 0, 0, 0);
        }

        // ship C rows 2,3 to partner lane (+32); every lane then handles 2 rows
        float p0[4], p1[4];
        #pragma unroll
        for (int g = 0; g < 4; ++g) {
            const float t2 = __shfl_xor(acc[g][2], 32, 64);
            const float t3 = __shfl_xor(acc[g][3], 32, 64);
            p0[g] = hi ? t2 : acc[g][0];
            p1[g] = hi ? t3 : acc[g][1];
        }

        // gates via raw v_exp_f32 (log2e folded into weights/bias)
        const float ig0 = rcp_f(1.0f + exp2_f(-p0[0]));
        const float og0 = rcp_f(1.0f + exp2_f(-p0[1]));
        const float fg0 = rcp_f(1.0f + exp2_f(-p0[2]));
        const float cg0 = 1.0f - 2.0f * rcp_f(exp2_f(p0[3]) + 1.0f);
        const float ig1 = rcp_f(1.0f + exp2_f(-p1[0]));
        const float og1 = rcp_f(1.0f + exp2_f(-p1[1]));
        const float fg1 = rcp_f(1.0f + exp2_f(-p1[2]));
        const float cg1 = 1.0f - 2.0f * rcp_f(exp2_f(p1[3]) + 1.0f);
        cst0 = fmaf(fg0, cst0, ig0 * cg0);
        cst1 = fmaf(fg1, cst1, ig1 * cg1);
        const float h0 = og0 * (1.0f - 2.0f * rcp_f(exp2_f(cst0 * SC_TANH) + 1.0f));
        const float h1 = og1 * (1.0f - 2.0f * rcp_f(exp2_f(cst1 * SC_TANH) + 1.0f));

        // h -> history row t+1 (recurrence input AND attention history)
        hh[t + 1][rowbase][dcol]     = (_Float16)h0;
        hh[t + 1][rowbase + 1][dcol] = (_Float16)h1;

        __syncthreads();   // single barrier: h(t) visible for step t+1
    }

    // ---- deferred attention: wave w handles batches 2w, 2w+1 ----
    const float* wtg = Wt + (size_t)n * (TT * 64);
    #pragma unroll
    for (int bb = 0; bb < 2; ++bb) {
        const int b = 2 * w + bb;
        float s[TT];
        #pragma unroll
        for (int t = 0; t < TT; ++t)
            s[t] = (float)hh[t + 1][b][lane] * wtg[t * 64 + lane];
        #pragma unroll
        for (int t = 0; t < TT; ++t) {
            #pragma unroll
            for (int mk = 32; mk >= 1; mk >>= 1)
                s[t] += __shfl_xor(s[t], mk, 64);
        }
        float m = s[0];
        #pragma unroll
        for (int t = 1; t < TT; ++t) m = fmaxf(m, s[t]);
        float se = 0.f;
        #pragma unroll
        for (int t = 0; t < TT; ++t) { s[t] = exp2_f((s[t] - m) * SC_SIG); se += s[t]; }
        const float rs = rcp_f(se);
        float o = 0.f;
        #pragma unroll
        for (int t = 0; t < TT; ++t)
            o = fmaf(s[t], (float)hh[t + 1][b][lane], o);
        out[((size_t)b * NSTK + n) * 64 + lane] = o * rs;
    }
}

extern "C" void kernel_launch(void* const* d_in, const int* in_sizes, int n_in,
                              void* d_out, int out_size, void* d_ws, size_t ws_size,
                              hipStream_t stream) {
    const float* x  = (const float*)d_in[0];
    const float* Wi = (const float*)d_in[1];
    const float* bi = (const float*)d_in[2];
    const float* Wo = (const float*)d_in[3];
    const float* bo = (const float*)d_in[4];
    const float* Wf = (const float*)d_in[5];
    const float* bf = (const float*)d_in[6];
    const float* Wc = (const float*)d_in[7];
    const float* bc = (const float*)d_in[8];
    const float* Wt = (const float*)d_in[9];
    float* out = (float*)d_out;

    lstm_att_lean<<<NSTK, THREADS, 0, stream>>>(
        x, Wi, bi, Wo, bo, Wf, bf, Wc, bc, Wt, out);
}

// Round 12
// 65.017 us; speedup vs baseline: 1.0584x; 1.0584x over previous
//
#include <hip/hip_runtime.h>

#define TT 20
#define NSTK 1000
#define THREADS 256
#define HP 72               // padded f16 row stride (144 B): frag reads ~4-way on tiny payload,
                            // scalar h/x writes and tail row reads 2-way (free)

#define SC_SIG  1.44269504089f      // log2(e)
#define SC_TANH 2.88539008178f      // 2*log2(e)

typedef float f32x4 __attribute__((ext_vector_type(4)));
typedef _Float16 f16x8 __attribute__((ext_vector_type(8)));
typedef _Float16 f16x2 __attribute__((ext_vector_type(2)));

__device__ __forceinline__ float rcp_f(float x) { return __builtin_amdgcn_rcpf(x); }
__device__ __forceinline__ float exp2_f(float x) { return __builtin_amdgcn_exp2f(x); }

// A/B fragment k-convention: k = kf*32 + q*8 + j  (q = lane>>4, j = elem).
// Same bijection for A and B, so the true HW k-permutation cancels.
// A-operands read straight from row-major padded LDS rows:
//   af[0,1] = x[brow][(kf&1)*32 + q*8 ..+7],  af[2,3] = h[brow][...]
// Rows r16>=8 duplicate r16-8 (same LDS addr -> broadcast, free); their C rows are discarded.

extern "C" __global__ void __launch_bounds__(THREADS, 4)
lstm_att_v11(const float* __restrict__ x,
             const float* __restrict__ Wi, const float* __restrict__ bi,
             const float* __restrict__ Wo, const float* __restrict__ bo,
             const float* __restrict__ Wf, const float* __restrict__ bf_,
             const float* __restrict__ Wc, const float* __restrict__ bc,
             const float* __restrict__ Wt,
             float* __restrict__ out)
{
    __shared__ __align__(16) _Float16 hh[TT + 1][8][HP];  // 24.2 KB: h history + recurrence exchange
    __shared__ __align__(16) _Float16 xb[2][8][HP];       // 2.3 KB: x staging, double-buffered

    const int n    = blockIdx.x;
    const int tid  = threadIdx.x;
    const int lane = tid & 63;
    const int w    = tid >> 6;            // wave 0..3
    const int q    = lane >> 4;           // k-subgroup
    const int r16  = lane & 15;           // A row / B col within frag
    const int brow = r16 & 7;             // batch row this lane reads (8-15 dup -> broadcast)
    const int dcol = w * 16 + r16;        // this lane's d column (0..63)
    const bool hi  = lane >= 32;
    const int rowbase = ((lane & 31) >> 4) * 4 + (hi ? 2 : 0);  // this lane's 2 batch rows

    // ---- weight B-frags, strided scalar loads (R4 pattern), log2e-prescaled ----
    f16x8 bw[4][4];
    float biasv[4];
    {
        const float* Wg[4] = {Wi, Wo, Wf, Wc};
        const float* Bg[4] = {bi, bo, bf_, bc};
        #pragma unroll
        for (int g = 0; g < 4; ++g) {
            const float sc = (g == 3) ? SC_TANH : SC_SIG;
            const float* base = Wg[g] + (size_t)n * 8192 + dcol;
            #pragma unroll
            for (int kf = 0; kf < 4; ++kf)
                #pragma unroll
                for (int j = 0; j < 8; ++j)
                    bw[g][kf][j] = (_Float16)(base[(kf * 32 + q * 8 + j) * 64] * sc);
            biasv[g] = Bg[g][n * 64 + dcol] * sc;
        }
    }

    // ---- x staging role: thread -> (batch sb, dims dx,dx+1) ----
    const int sb = tid >> 5, dx = (tid & 31) * 2;
    const float* xptr = x + ((size_t)sb * TT * NSTK + (size_t)n) * 64 + dx;

    // init: stage x(t=0) into xb[0]; zero hh[0]; prefetch x(t=1)
    {
        const float2 x0 = *(const float2*)xptr;
        *(f16x2*)(&xb[0][sb][dx]) = (f16x2){(_Float16)x0.x, (_Float16)x0.y};
    }
    for (int i = tid; i < 8 * HP / 2; i += THREADS) ((unsigned*)hh)[i] = 0u;
    float2 xreg = *(const float2*)(xptr + (size_t)NSTK * 64);

    float cst0 = 0.f, cst1 = 0.f;         // cell state for rows rowbase, rowbase+1 at dcol
    __syncthreads();

    for (int t = 0; t < TT; ++t) {
        const int cur = t & 1, nxt = cur ^ 1;

        // A-operands: 4 x ds_read_b128 issued together; compiler's fine lgkmcnt
        // lets the x-MFMAs start while the h reads land
        f16x8 af[4];
        af[0] = *(const f16x8*)(&xb[cur][brow][q * 8]);
        af[1] = *(const f16x8*)(&xb[cur][brow][32 + q * 8]);
        af[2] = *(const f16x8*)(&hh[t][brow][q * 8]);
        af[3] = *(const f16x8*)(&hh[t][brow][32 + q * 8]);

        // stage x(t+1) into next buffer; prefetch t+2 (hidden under MFMA)
        if (t + 1 < TT)
            *(f16x2*)(&xb[nxt][sb][dx]) = (f16x2){(_Float16)xreg.x, (_Float16)xreg.y};
        {
            const size_t off = (size_t)((t + 2 < TT) ? t + 2 : TT - 1) * (NSTK * 64);
            xreg = *(const float2*)(xptr + off);
        }

        f32x4 acc[4];
        #pragma unroll
        for (int g = 0; g < 4; ++g)
            acc[g] = (f32x4){biasv[g], biasv[g], biasv[g], biasv[g]};
        #pragma unroll
        for (int kf = 0; kf < 4; ++kf) {
            #pragma unroll
            for (int g = 0; g < 4; ++g)
                acc[g] = __builtin_amdgcn_mfma_f32_16x16x32_f16(af[kf], bw[g][kf], acc[g], 0, 0, 0);
        }

        // ship C rows 2,3 to partner lane (+32); every lane then handles 2 rows
        float p0[4], p1[4];
        #pragma unroll
        for (int g = 0; g < 4; ++g) {
            const float t2 = __shfl_xor(acc[g][2], 32, 64);
            const float t3 = __shfl_xor(acc[g][3], 32, 64);
            p0[g] = hi ? t2 : acc[g][0];
            p1[g] = hi ? t3 : acc[g][1];
        }

        // gates via raw v_exp_f32 (log2e folded into weights/bias)
        const float ig0 = rcp_f(1.0f + exp2_f(-p0[0]));
        const float og0 = rcp_f(1.0f + exp2_f(-p0[1]));
        const float fg0 = rcp_f(1.0f + exp2_f(-p0[2]));
        const float cg0 = 1.0f - 2.0f * rcp_f(exp2_f(p0[3]) + 1.0f);
        const float ig1 = rcp_f(1.0f + exp2_f(-p1[0]));
        const float og1 = rcp_f(1.0f + exp2_f(-p1[1]));
        const float fg1 = rcp_f(1.0f + exp2_f(-p1[2]));
        const float cg1 = 1.0f - 2.0f * rcp_f(exp2_f(p1[3]) + 1.0f);
        cst0 = fmaf(fg0, cst0, ig0 * cg0);
        cst1 = fmaf(fg1, cst1, ig1 * cg1);
        const float h0 = og0 * (1.0f - 2.0f * rcp_f(exp2_f(cst0 * SC_TANH) + 1.0f));
        const float h1 = og1 * (1.0f - 2.0f * rcp_f(exp2_f(cst1 * SC_TANH) + 1.0f));

        // single h store per row: recurrence input AND attention history (2-way banks: free)
        hh[t + 1][rowbase][dcol]     = (_Float16)h0;
        hh[t + 1][rowbase + 1][dcol] = (_Float16)h1;

        __syncthreads();   // h(t) + x(t+1) visible for step t+1
    }

    // ---- deferred attention: wave w handles batches 2w, 2w+1 (R4 tail, hh-indexed) ----
    const float* wtg = Wt + (size_t)n * (TT * 64);
    #pragma unroll
    for (int bb = 0; bb < 2; ++bb) {
        const int b = 2 * w + bb;
        float s[TT];
        #pragma unroll
        for (int t = 0; t < TT; ++t)
            s[t] = (float)hh[t + 1][b][lane] * wtg[t * 64 + lane];
        #pragma unroll
        for (int t = 0; t < TT; ++t) {
            #pragma unroll
            for (int mk = 32; mk >= 1; mk >>= 1)
                s[t] += __shfl_xor(s[t], mk, 64);
        }
        float m = s[0];
        #pragma unroll
        for (int t = 1; t < TT; ++t) m = fmaxf(m, s[t]);
        float se = 0.f;
        #pragma unroll
        for (int t = 0; t < TT; ++t) { s[t] = exp2_f((s[t] - m) * SC_SIG); se += s[t]; }
        const float rs = rcp_f(se);
        float o = 0.f;
        #pragma unroll
        for (int t = 0; t < TT; ++t)
            o = fmaf(s[t], (float)hh[t + 1][b][lane], o);
        out[((size_t)b * NSTK + n) * 64 + lane] = o * rs;
    }
}

extern "C" void kernel_launch(void* const* d_in, const int* in_sizes, int n_in,
                              void* d_out, int out_size, void* d_ws, size_t ws_size,
                              hipStream_t stream) {
    const float* x  = (const float*)d_in[0];
    const float* Wi = (const float*)d_in[1];
    const float* bi = (const float*)d_in[2];
    const float* Wo = (const float*)d_in[3];
    const float* bo = (const float*)d_in[4];
    const float* Wf = (const float*)d_in[5];
    const float* bf = (const float*)d_in[6];
    const float* Wc = (const float*)d_in[7];
    const float* bc = (const float*)d_in[8];
    const float* Wt = (const float*)d_in[9];
    float* out = (float*)d_out;

    lstm_att_v11<<<NSTK, THREADS, 0, stream>>>(
        x, Wi, bi, Wo, bo, Wf, bf, Wc, bc, Wt, out);
}